// Round 13
// baseline (824.737 us; speedup 1.0000x reference)
//
#include <hip/hip_runtime.h>
#include <hip/hip_bf16.h>
#include <cstdint>

typedef unsigned short u16;
typedef __attribute__((ext_vector_type(8))) _Float16 f16x8;
typedef __attribute__((ext_vector_type(4))) float f32x4;
typedef __attribute__((ext_vector_type(16))) float f32x16;
typedef __attribute__((ext_vector_type(8))) unsigned short u16x8;

typedef const __attribute__((address_space(1))) void* gas1p;
typedef __attribute__((address_space(3))) void* las3p;
typedef const __attribute__((address_space(3))) u16* lc16p;

__device__ __forceinline__ void gld_lds16(const void* g, void* l) {
    __builtin_amdgcn_global_load_lds((gas1p)g, (las3p)l, 16, 0, 0);
}

// clobber-free asm ds_read_b128 with byte-immediate offset
template<int OFF>
__device__ __forceinline__ f16x8 dsr128o(const u16* p) {
    f16x8 r;
    asm volatile("ds_read_b128 %0, %1 offset:%2" : "=v"(r) : "v"((lc16p)p), "i"(OFF));
    return r;
}

__device__ __forceinline__ u16 f2h(float f) {
    _Float16 h = (_Float16)f;
    return __builtin_bit_cast(u16, h);
}

// ---------------- prep: x fp32 -> fp16 ----------------
__global__ void cvt_x_kernel(const float4* __restrict__ x, u16* __restrict__ xb) {
    size_t i = (size_t)blockIdx.x * blockDim.x + threadIdx.x;
    float4 a = x[2 * i];
    float4 b = x[2 * i + 1];
    u16x8 o;
    o[0] = f2h(a.x); o[1] = f2h(a.y); o[2] = f2h(a.z); o[3] = f2h(a.w);
    o[4] = f2h(b.x); o[5] = f2h(b.y); o[6] = f2h(b.z); o[7] = f2h(b.w);
    *(u16x8*)&xb[i * 8] = o;
}

// ---------------- prep: weight norm, all 5 layers in 2 launches ----------------
struct WnDesc {
    const float* v; const float* g; u16* wT; float* partial;
    int K; int N; int blk0;
};
struct WnPack { WnDesc d[5]; int nlayer; };

__global__ void wn_partial_all(WnPack p) {
    int b = blockIdx.x;
    int l = 0;
    while (l + 1 < p.nlayer && b >= p.d[l + 1].blk0) l++;
    const WnDesc& d = p.d[l];
    int lb = b - d.blk0;
    int nbx = d.N >> 6;
    int bx = lb % nbx, seg = lb / nbx;

    int lane = threadIdx.x & 63;
    int tr = threadIdx.x >> 6;
    int n = bx * 64 + lane;
    int kseg = d.K >> 3;
    int kbeg = seg * kseg;
    float s = 0.f;
    for (int k = kbeg + tr; k < kbeg + kseg; k += 4) {
        float x = d.v[(size_t)k * d.N + n];
        s += x * x;
    }
    __shared__ float red[4][64];
    red[tr][lane] = s;
    __syncthreads();
    if (tr == 0)
        d.partial[seg * d.N + n] = red[0][lane] + red[1][lane] + red[2][lane] + red[3][lane];
}

__global__ void wn_write_all(WnPack p) {
    int b = blockIdx.x;
    int l = 0;
    while (l + 1 < p.nlayer && b >= p.d[l + 1].blk0) l++;
    const WnDesc& d = p.d[l];
    int lb = b - d.blk0;
    int nbx = d.N >> 6;
    int bx = lb % nbx, seg = lb / nbx;

    int lane = threadIdx.x & 63;
    int tr = threadIdx.x >> 6;
    int n = bx * 64 + lane;
    float s = 0.f;
#pragma unroll
    for (int i = 0; i < 8; i++) s += d.partial[i * d.N + n];
    float sc = d.g[n] / sqrtf(s);

    int kseg = d.K >> 3;
    int kbeg = seg * kseg;
    for (int k = kbeg + tr; k < kbeg + kseg; k += 4)
        d.wT[(size_t)n * d.K + k] = f2h(d.v[(size_t)k * d.N + n] * sc);
}

// ---------------- main GEMM: 128x256 tile, BK=32, 8 waves, 32x32x16 MFMA -------
// A/B test vs R12: same tile, same LDS traffic, HALF the MFMA instructions
// (8x mfma_f32_32x32x16_f16 per wave-tile instead of 16x 16x16x32) at a higher
// ceiling (2382 vs 2075 TF). Decisive between MFMA-issue-bound vs LDS-bound.
// Swizzle fixed: phys slot q = (s + (row>>1)) & 3 -> the 8 rows aliasing each
// 128B bank-line spread 2-per-slot (2-way = free). Inverse on staging source.
// Operand maps: A,B row/col = lane&31, k = (lane>>5)*8+j (analog of verified
// 16x16 map); C/D col=lane&31, row=(reg&3)+8*(reg>>2)+4*(lane>>5) [m74/m101].
template<int N, int K, bool ACT, bool OUTF32>
__global__ __launch_bounds__(512, 4) void gemm_mb2(
    const u16* __restrict__ A, const u16* __restrict__ Bt,
    u16* __restrict__ Ch, float* __restrict__ Cf)
{
    constexpr int M = 65536;
    constexpr int NT = K / 32;          // K-tiles
    constexpr int NTN = N / 256;
    constexpr int NWG = (M / 128) * NTN;

    __shared__ u16 sA[2][128 * 32];     // 8 KB each
    __shared__ u16 sB[2][256 * 32];     // 16 KB each

    const int bid = blockIdx.x;
    const int wk = (bid & 7) * (NWG >> 3) + (bid >> 3);   // bijective: NWG%8==0
    const int tm = wk / NTN, tn = wk % NTN;
    const long m0 = (long)tm * 128;
    const int n0 = tn * 256;

    const int tid = threadIdx.x;
    const int lane = tid & 63;
    const int wid = tid >> 6;
    const int wm = (wid >> 2) * 64;     // 2 m-waves
    const int wn = (wid & 3) * 64;      // 4 n-waves

    // ---- staging: 3 gld_lds per tile; inverse-swizzled global k-slot ----
    const int r4 = tid >> 2;                           // staged row 0..127
    const int sG = ((tid & 3) - (r4 >> 1)) & 3;        // logical slot for phys tid&3
    const u16* Ab  = A  + (m0 + r4) * (size_t)K + sG * 8;
    const u16* Bb  = Bt + (size_t)(n0 + r4) * K + sG * 8;
    const u16* Bb2 = Bt + (size_t)(n0 + 128 + r4) * K + sG * 8;
    const int dst8 = tid * 8;

    auto stage = [&](int buf, int t) {
        gld_lds16(Ab + (size_t)t * 32, &sA[buf][dst8]);
        gld_lds16(Bb + (size_t)t * 32, &sB[buf][dst8]);
        gld_lds16(Bb2 + (size_t)t * 32, &sB[buf][4096 + dst8]);
    };

    // ---- fragment read bases (swizzled): slot q = (k_oct + (row>>1)) & 3 ----
    const int lrow = lane & 31;
    const int ls = lane >> 5;                          // k-octet selector
    const int q0 = (ls + (lrow >> 1)) & 3;             // k-step 0
    const int q1 = q0 ^ 2;                             // k-step 1 (= +2 mod 4)
    const int aoff0 = (wm + lrow) * 32 + q0 * 8;
    const int aoff1 = (wm + lrow) * 32 + q1 * 8;
    const int boff0 = (wn + lrow) * 32 + q0 * 8;
    const int boff1 = (wn + lrow) * 32 + q1 * 8;

    f32x16 acc[2][2] = {};
    f16x8 a0[2], a1[2], b0[2], b1[2];

    auto BAR = [&]() { __builtin_amdgcn_s_barrier(); };
#define LGKM(n) { asm volatile("s_waitcnt lgkmcnt(" #n ")"); __builtin_amdgcn_sched_barrier(0); }
#define VMC0  { asm volatile("s_waitcnt vmcnt(0)");  __builtin_amdgcn_sched_barrier(0); }

    // ---- prologue ----
    stage(0, 0);
    VMC0;
    BAR();

    // ---- main loop ----
    for (int t = 0; t < NT; t++) {
        const int cur = t & 1, nxt = cur ^ 1;
        if (t + 1 < NT) stage(nxt, t + 1);

        const u16* pA0 = &sA[cur][aoff0];
        const u16* pA1 = &sA[cur][aoff1];
        const u16* pB0 = &sB[cur][boff0];
        const u16* pB1 = &sB[cur][boff1];
        a0[0] = dsr128o<0>(pA0); a0[1] = dsr128o<2048>(pA0);   // k0, frags 0,1
        b0[0] = dsr128o<0>(pB0); b0[1] = dsr128o<2048>(pB0);
        a1[0] = dsr128o<0>(pA1); a1[1] = dsr128o<2048>(pA1);   // k1
        b1[0] = dsr128o<0>(pB1); b1[1] = dsr128o<2048>(pB1);

        LGKM(4);   // k0 operands ready; k1 reads drain under k0 MFMAs
        __builtin_amdgcn_s_setprio(1);
#pragma unroll
        for (int i = 0; i < 2; i++)
#pragma unroll
            for (int j = 0; j < 2; j++)
                acc[i][j] = __builtin_amdgcn_mfma_f32_32x32x16_f16(a0[i], b0[j], acc[i][j], 0, 0, 0);
        __builtin_amdgcn_s_setprio(0);
        LGKM(0);
        __builtin_amdgcn_s_setprio(1);
#pragma unroll
        for (int i = 0; i < 2; i++)
#pragma unroll
            for (int j = 0; j < 2; j++)
                acc[i][j] = __builtin_amdgcn_mfma_f32_32x32x16_f16(a1[i], b1[j], acc[i][j], 0, 0, 0);
        __builtin_amdgcn_s_setprio(0);

        if (t + 1 < NT) {
            VMC0;      // forces stage(t+1); drain hidden by co-resident block
            BAR();
        }
    }
#undef LGKM
#undef VMC0

    // ---- epilogue: C/D col = lane&31, row = (reg&3)+8*(reg>>2)+4*(lane>>5) ----
    const long crowb = m0 + wm + 4 * (lane >> 5);
    const int ccolb = n0 + wn + (lane & 31);
#pragma unroll
    for (int fi = 0; fi < 2; fi++) {
#pragma unroll
        for (int fj = 0; fj < 2; fj++) {
#pragma unroll
            for (int reg = 0; reg < 16; reg++) {
                const long row = crowb + fi * 32 + (reg & 3) + 8 * (reg >> 2);
                float v = acc[fi][fj][reg];
                if (ACT) v = fmaxf(v, 0.f) + __logf(1.f + __expf(-fabsf(v)));
                const size_t idx = (size_t)row * N + ccolb + fj * 32;
                if (OUTF32) Cf[idx] = v;
                else        Ch[idx] = f2h(v);
            }
        }
    }
}

// ---------------- launch ----------------
extern "C" void kernel_launch(void* const* d_in, const int* in_sizes, int n_in,
                              void* d_out, int out_size, void* d_ws, size_t ws_size,
                              hipStream_t stream) {
    const float* x  = (const float*)d_in[0];
    const float* v1 = (const float*)d_in[1];
    const float* g1 = (const float*)d_in[2];
    const float* v2 = (const float*)d_in[3];
    const float* g2 = (const float*)d_in[4];
    const float* v3 = (const float*)d_in[5];
    const float* g3 = (const float*)d_in[6];
    const float* v4 = (const float*)d_in[7];
    const float* g4 = (const float*)d_in[8];
    const float* v5 = (const float*)d_in[9];
    const float* g5 = (const float*)d_in[10];
    float* out = (float*)d_out;

    const int M = 65536;
    char* ws = (char*)d_ws;
    u16* bufA = (u16*)(ws);                          // 128 MB
    u16* bufB = (u16*)(ws + 0x8000000ULL);           // 128 MB
    u16* w1T  = (u16*)(ws + 0x10000000ULL);
    u16* w2T  = w1T + 1024 * 512;
    u16* w3T  = w2T + 1024 * 1024;
    u16* w4T  = w3T + 1024 * 1024;
    u16* w5T  = w4T + 1024 * 1024;
    float* part = (float*)(ws + 0x10800000ULL);      // 5 x 8 x 1024 f32

    cvt_x_kernel<<<(M * 512) / (256 * 8), 256, 0, stream>>>((const float4*)x, bufB);

    WnPack pk;
    int cum = 0;
    auto mk = [&](int i, const float* v, const float* g, u16* wT, int K, int N) {
        pk.d[i] = WnDesc{v, g, wT, part + i * 8 * 1024, K, N, cum};
        cum += (N / 64) * 8;
    };
    mk(0, v1, g1, w1T, 512, 1024);
    mk(1, v2, g2, w2T, 1024, 1024);
    mk(2, v3, g3, w3T, 1024, 1024);
    mk(3, v4, g4, w4T, 1024, 1024);
    mk(4, v5, g5, w5T, 1024, 512);
    pk.nlayer = 5;

    wn_partial_all<<<cum, 256, 0, stream>>>(pk);
    wn_write_all<<<cum, 256, 0, stream>>>(pk);

    gemm_mb2<1024, 512,  true,  false><<<2048, 512, 0, stream>>>(bufB, w1T, bufA, nullptr);
    gemm_mb2<1024, 1024, true,  false><<<2048, 512, 0, stream>>>(bufA, w2T, bufB, nullptr);
    gemm_mb2<1024, 1024, true,  false><<<2048, 512, 0, stream>>>(bufB, w3T, bufA, nullptr);
    gemm_mb2<1024, 1024, true,  false><<<2048, 512, 0, stream>>>(bufA, w4T, bufB, nullptr);
    gemm_mb2<512,  1024, false, true ><<<1024, 512, 0, stream>>>(bufB, w5T, nullptr, out);

    (void)in_sizes; (void)n_in; (void)out_size; (void)ws_size;
}